// Round 5
// baseline (128.138 us; speedup 1.0000x reference)
//
#include <hip/hip_runtime.h>

#define NB 4096
#define MM 128
#define NN 96
#define LL 20

// One block (256 threads = 4 waves) per batch.
// matvec roles: thread (rg = tid>>3 in 0..31, cg = tid&7) owns
//   H[rg*4 .. rg*4+3][cg*12 .. cg*12+11] in 48 registers (FORCED resident).
// gather roles: thread pair (2c, 2c+1) owns column c (tid<192), each sums 16
//   of 32 wp rows, combines via shfl_xor(1), updates redundantly.
// Per iteration: 2 barriers.
__global__ __launch_bounds__(256) __attribute__((amdgpu_waves_per_eu(2, 4)))
void pg_kernel(const float* __restrict__ x_ini,
               const float* __restrict__ y,
               const float* __restrict__ H,
               const float* __restrict__ xt,
               const float* __restrict__ grad_ss,
               const float* __restrict__ extra_ss,
               const float* __restrict__ gamma1,
               float* __restrict__ out)
{
    const int b   = blockIdx.x;
    const int tid = threadIdx.x;
    const int cg  = tid & 7;    // column group: cols cg*12 .. +11
    const int rg  = tid >> 3;   // row group:    rows rg*4  .. +3

    __shared__ __align__(16) float wp[32][100];  // 400B row stride; measured 0 conflicts
    __shared__ __align__(16) float yxb[NN];
    __shared__ float pgs[LL], pes[LL], pgm[LL];
    __shared__ float lsum[4];

    if (tid < LL) { pgs[tid] = grad_ss[tid]; pes[tid] = extra_ss[tid]; pgm[tid] = gamma1[tid]; }

    // ---- own H tile -> registers; pin so LICM/RA cannot re-stream it ----
    float h[4][12];
    const float* Hb = H + (size_t)b * (MM * NN) + (size_t)(rg * 4) * NN + cg * 12;
    #pragma unroll
    for (int i = 0; i < 4; ++i) {
        #pragma unroll
        for (int k = 0; k < 3; ++k) {
            float4 v = *reinterpret_cast<const float4*>(Hb + i * NN + 4 * k);
            h[i][4*k+0] = v.x; h[i][4*k+1] = v.y;
            h[i][4*k+2] = v.z; h[i][4*k+3] = v.w;
        }
    }
    #pragma unroll
    for (int i = 0; i < 4; ++i)
        #pragma unroll
        for (int j = 0; j < 12; ++j)
            asm volatile("" : "+v"(h[i][j]));

    // ---- own rows of y ----
    float yr[4];
    {
        float4 v = *reinterpret_cast<const float4*>(y + (size_t)b * MM + rg * 4);
        yr[0] = v.x; yr[1] = v.y; yr[2] = v.z; yr[3] = v.w;
    }

    // ---- gather-role state: column col, two redundant copies (half=0/1) ----
    const int col  = tid >> 1;
    const int half = tid & 1;
    float yx_own = 0.f, x_c = 0.f;
    if (tid < 192) {
        yx_own = x_ini[(size_t)b * NN + col];
        x_c    = yx_own;
        if (!half) yxb[col] = yx_own;
    }
    __syncthreads();

    float yx[12];
    #pragma unroll
    for (int k = 0; k < 3; ++k) {
        float4 v = *reinterpret_cast<const float4*>(&yxb[cg * 12 + 4 * k]);
        yx[4*k+0]=v.x; yx[4*k+1]=v.y; yx[4*k+2]=v.z; yx[4*k+3]=v.w;
    }

    for (int t = 0; t < LL; ++t) {
        // ---- matvec1: u = H*yx partials over own 12 cols ----
        float u[4];
        #pragma unroll
        for (int i = 0; i < 4; ++i) {
            float s = 0.f;
            #pragma unroll
            for (int j = 0; j < 12; ++j) s = fmaf(h[i][j], yx[j], s);
            u[i] = s;
        }
        #pragma unroll
        for (int m = 1; m <= 4; m <<= 1) {
            #pragma unroll
            for (int i = 0; i < 4; ++i) u[i] += __shfl_xor(u[i], m, 64);
        }
        #pragma unroll
        for (int i = 0; i < 4; ++i) u[i] -= yr[i];

        // ---- matvec2 partials: wp[rg][c] = sum_i h[i][c]*u[i] ----
        #pragma unroll
        for (int k = 0; k < 3; ++k) {
            float4 s;
            s.x = fmaf(h[0][4*k+0], u[0], fmaf(h[1][4*k+0], u[1], fmaf(h[2][4*k+0], u[2], h[3][4*k+0] * u[3])));
            s.y = fmaf(h[0][4*k+1], u[0], fmaf(h[1][4*k+1], u[1], fmaf(h[2][4*k+1], u[2], h[3][4*k+1] * u[3])));
            s.z = fmaf(h[0][4*k+2], u[0], fmaf(h[1][4*k+2], u[1], fmaf(h[2][4*k+2], u[2], h[3][4*k+2] * u[3])));
            s.w = fmaf(h[0][4*k+3], u[0], fmaf(h[1][4*k+3], u[1], fmaf(h[2][4*k+3], u[2], h[3][4*k+3] * u[3])));
            *reinterpret_cast<float4*>(&wp[rg][cg * 12 + 4 * k]) = s;
        }
        __syncthreads();   // B1: scatter visible

        // ---- gather + elementwise by column pairs (192 threads) ----
        if (tid < 192) {
            const int rbase = half * 16;
            float a0 = 0.f, a1 = 0.f, a2 = 0.f, a3 = 0.f;
            #pragma unroll
            for (int r = 0; r < 4; ++r) {
                a0 += wp[rbase + 4*r + 0][col];
                a1 += wp[rbase + 4*r + 1][col];
                a2 += wp[rbase + 4*r + 2][col];
                a3 += wp[rbase + 4*r + 3][col];
            }
            float w = (a0 + a1) + (a2 + a3);
            w += __shfl_xor(w, 1, 64);                 // combine the two halves
            const float gs = pgs[t], es = pes[t], gm = pgm[t];
            float xb  = fmaf(-2.0f * gs, w, yx_own);   // y_x - 2*gs*H^T(H yx - y)
            float cen = 2.0f * fminf(fmaxf(rintf(xb * 0.5f), -1.0f), 1.0f);
            float z   = gm * (xb - cen);
            float e   = __expf(-z);
            float ply = fmaf(2.0f, __builtin_amdgcn_rcpf(1.0f + e), -1.0f);
            yx_own = fmaf(es, ply - x_c, ply);
            x_c    = ply;
            if (t + 1 < LL && !half) yxb[col] = yx_own;
        }
        if (t + 1 < LL) {
            __syncthreads();   // B2: yxb publish; also separates wp reads from next scatter
            #pragma unroll
            for (int k = 0; k < 3; ++k) {
                float4 v = *reinterpret_cast<const float4*>(&yxb[cg * 12 + 4 * k]);
                yx[4*k+0]=v.x; yx[4*k+1]=v.y; yx[4*k+2]=v.z; yx[4*k+3]=v.w;
            }
        }
    }

    // ---- epilogue: write x, accumulate loss (even lanes of pairs hold state) ----
    float part = 0.f;
    if (tid < 192 && !half) {
        out[(size_t)b * NN + col] = x_c;
        float d = x_c - xt[(size_t)b * NN + col];
        part = d * d;
    }
    #pragma unroll
    for (int m = 1; m < 64; m <<= 1) part += __shfl_xor(part, m, 64);
    if ((tid & 63) == 0) lsum[tid >> 6] = part;
    __syncthreads();
    if (tid == 0) atomicAdd(out + (size_t)NB * NN, (lsum[0] + lsum[1]) + (lsum[2] + lsum[3]));
}

extern "C" void kernel_launch(void* const* d_in, const int* in_sizes, int n_in,
                              void* d_out, int out_size, void* d_ws, size_t ws_size,
                              hipStream_t stream) {
    const float* x_ini    = (const float*)d_in[0];
    const float* y        = (const float*)d_in[1];
    const float* H        = (const float*)d_in[2];
    const float* xt       = (const float*)d_in[3];
    const float* grad_ss  = (const float*)d_in[4];
    const float* extra_ss = (const float*)d_in[5];
    const float* gamma1   = (const float*)d_in[6];
    float* out = (float*)d_out;

    hipMemsetAsync(out + (size_t)NB * NN, 0, sizeof(float), stream);
    pg_kernel<<<NB, 256, 0, stream>>>(x_ini, y, H, xt, grad_ss, extra_ss, gamma1, out);
}

// Round 6
// 125.795 us; speedup vs baseline: 1.0186x; 1.0186x over previous
//
#include <hip/hip_runtime.h>

#define NB 4096
#define MM 128
#define NN 96
#define LL 20

typedef __attribute__((ext_vector_type(8))) short bf16x8;
typedef __attribute__((ext_vector_type(4))) float f32x4;
typedef __attribute__((ext_vector_type(4))) unsigned int u32x4;

// ---- LDS union ----
// Phase A: Ht_hi [112 rows][72 bf16] (144B stride) at 0; Ht_lo at 16128.
//          row c = H column c (k along row); row 96 = y; rows 97..111 garbage.
// Phase B (aliased): HTHP packed u32[(hi bf16<<16)|lo bf16] [96][100], col 96 = HTy.
#define HT_HI      0
#define HT_LO      16128
#define HT_STRIDE  144
#define HTHP_STRIDE 400     // bytes (100 u32) -> uniform 2-way banks on C-write
#define U_SIZE     38400

#define SEL_HI 0x07060302u  // perm: [hi(k+1)|hi(k)] from packed pk1,pk
#define SEL_LO 0x05040100u  // perm: [lo(k+1)|lo(k)]

__device__ __forceinline__ unsigned bf16_rne(float f) {
    unsigned u = __float_as_uint(f);
    return (u + 0x7fffu + ((u >> 16) & 1u)) >> 16;
}
__device__ __forceinline__ unsigned pack_hl(float v) {
    unsigned hi = bf16_rne(v);
    unsigned lo = bf16_rne(v - __uint_as_float(hi << 16));
    return (hi << 16) | (lo & 0xffffu);
}
__device__ __forceinline__ bf16x8 mk8(unsigned a, unsigned b, unsigned c, unsigned d) {
    u32x4 t; t[0] = a; t[1] = b; t[2] = c; t[3] = d;
    return __builtin_bit_cast(bf16x8, t);
}

__global__ __launch_bounds__(128) __attribute__((amdgpu_waves_per_eu(2)))
void pg_kernel(const float* __restrict__ x_ini,
               const float* __restrict__ y,
               const float* __restrict__ H,
               const float* __restrict__ xt,
               const float* __restrict__ grad_ss,
               const float* __restrict__ extra_ss,
               const float* __restrict__ gamma1,
               float* __restrict__ out)
{
    __shared__ __align__(16) char U[U_SIZE];
    __shared__ __align__(16) unsigned yxP[2][NN];   // packed hi|lo yx, double-buffered
    __shared__ float pgs[LL], pes[LL], pgm[LL];
    __shared__ float lsum[2];

    const int b    = blockIdx.x;
    const int tid  = threadIdx.x;
    const int lane = tid & 63;
    const int wid  = tid >> 6;

    if (tid < LL) { pgs[tid] = grad_ss[tid]; pes[tid] = extra_ss[tid]; pgm[tid] = gamma1[tid]; }

    // ================= Phase A: [H|y]^T [H|y] via split-bf16 MFMA (R2-verified) ============
    f32x4 acc[3][7];
    #pragma unroll
    for (int i = 0; i < 3; ++i)
        #pragma unroll
        for (int j = 0; j < 7; ++j)
            #pragma unroll
            for (int r = 0; r < 4; ++r) acc[i][j][r] = 0.f;

    const int c32 = tid & 31;
    const int ko  = tid >> 5;
    const float* Hb = H + (size_t)b * (MM * NN);

    for (int kh = 0; kh < 2; ++kh) {
        if (kh) __syncthreads();
        #pragma unroll
        for (int cg = 0; cg < 3; ++cg) {
            const int c = c32 + 32 * cg;
            float v[16];
            #pragma unroll
            for (int rr = 0; rr < 16; ++rr)
                v[rr] = Hb[(size_t)(kh * 64 + ko * 16 + rr) * NN + c];
            bf16x8 h0, h1, l0, l1;
            #pragma unroll
            for (int j = 0; j < 8; ++j) {
                unsigned ha = bf16_rne(v[j]);
                unsigned hb2 = bf16_rne(v[8 + j]);
                h0[j] = (short)ha;
                h1[j] = (short)hb2;
                l0[j] = (short)bf16_rne(v[j]     - __uint_as_float(ha  << 16));
                l1[j] = (short)bf16_rne(v[8 + j] - __uint_as_float(hb2 << 16));
            }
            char* ph = &U[HT_HI + c * HT_STRIDE + ko * 32];
            char* pl = &U[HT_LO + c * HT_STRIDE + ko * 32];
            *(bf16x8*)(ph)      = h0;
            *(bf16x8*)(ph + 16) = h1;
            *(bf16x8*)(pl)      = l0;
            *(bf16x8*)(pl + 16) = l1;
        }
        if (tid < 64) {
            float vy = y[(size_t)b * MM + kh * 64 + tid];
            unsigned hb2 = bf16_rne(vy);
            float lo = vy - __uint_as_float(hb2 << 16);
            *(unsigned short*)&U[HT_HI + 96 * HT_STRIDE + tid * 2] = (unsigned short)hb2;
            *(unsigned short*)&U[HT_LO + 96 * HT_STRIDE + tid * 2] = (unsigned short)bf16_rne(lo);
        }
        __syncthreads();

        #pragma unroll
        for (int kk = 0; kk < 2; ++kk) {
            const int kb = kk * 64 + (lane >> 4) * 16;
            bf16x8 Ah[3], Al[3], Bh[7], Bl[7];
            #pragma unroll
            for (int i = 0; i < 3; ++i) {
                const int off = (wid * 48 + i * 16 + (lane & 15)) * HT_STRIDE + kb;
                Ah[i] = *(const bf16x8*)&U[HT_HI + off];
                Al[i] = *(const bf16x8*)&U[HT_LO + off];
            }
            #pragma unroll
            for (int j = 0; j < 7; ++j) {
                const int off = (j * 16 + (lane & 15)) * HT_STRIDE + kb;
                Bh[j] = *(const bf16x8*)&U[HT_HI + off];
                Bl[j] = *(const bf16x8*)&U[HT_LO + off];
            }
            #pragma unroll
            for (int i = 0; i < 3; ++i)
                #pragma unroll
                for (int j = 0; j < 7; ++j) {
                    acc[i][j] = __builtin_amdgcn_mfma_f32_16x16x32_bf16(Ah[i], Bh[j], acc[i][j], 0, 0, 0);
                    acc[i][j] = __builtin_amdgcn_mfma_f32_16x16x32_bf16(Ah[i], Bl[j], acc[i][j], 0, 0, 0);
                    acc[i][j] = __builtin_amdgcn_mfma_f32_16x16x32_bf16(Al[i], Bh[j], acc[i][j], 0, 0, 0);
                }
        }
    }
    __syncthreads();   // all frag reads done -> safe to overwrite U

    // ---- C-write: pack f32 -> (hi|lo) u32 into HTHP[96][100] (layout m89-verified) ----
    #pragma unroll
    for (int i = 0; i < 3; ++i)
        #pragma unroll
        for (int j = 0; j < 7; ++j) {
            const int col = j * 16 + (lane & 15);
            if (col < 97) {
                const int rowb = wid * 48 + i * 16 + (lane >> 4) * 4;
                #pragma unroll
                for (int r = 0; r < 4; ++r)
                    *(unsigned*)&U[(rowb + r) * HTHP_STRIDE + col * 4] = pack_hl(acc[i][j][r]);
            }
        }

    // ---- elementwise-owner mapping: lane handles one row of its wave's 48 ----
    const int sel  = lane & 15;
    const bool act = sel < 12;
    const int msel = sel >> 2, rsel = sel & 3;
    const int row_g = wid * 48 + msel * 16 + (lane >> 4) * 4 + rsel;

    float yx_own = 0.f, x_c = 0.f, hty = 0.f;
    if (act) {
        yx_own = x_ini[(size_t)b * NN + row_g];
        x_c    = yx_own;
        yxP[0][row_g] = pack_hl(yx_own);
    }
    __syncthreads();   // HTHP + yxP[0] visible

    if (act) {
        unsigned p = *(const unsigned*)&U[row_g * HTHP_STRIDE + 96 * 4];
        hty = __uint_as_float(p & 0xffff0000u) + __uint_as_float(p << 16);
    }

    // ---- A-frags (HTH rows, hi/lo) -> registers, persistent for the loop ----
    bf16x8 ahi[3][3], alo[3][3];
    #pragma unroll
    for (int m = 0; m < 3; ++m) {
        const int row = wid * 48 + m * 16 + (lane & 15);
        #pragma unroll
        for (int kt = 0; kt < 3; ++kt) {
            const unsigned* p = (const unsigned*)&U[row * HTHP_STRIDE + (kt * 32 + (lane >> 4) * 8) * 4];
            u32x4 q0 = *(const u32x4*)p;
            u32x4 q1 = *(const u32x4*)(p + 4);
            ahi[m][kt] = mk8(__builtin_amdgcn_perm(q0[1], q0[0], SEL_HI),
                             __builtin_amdgcn_perm(q0[3], q0[2], SEL_HI),
                             __builtin_amdgcn_perm(q1[1], q1[0], SEL_HI),
                             __builtin_amdgcn_perm(q1[3], q1[2], SEL_HI));
            alo[m][kt] = mk8(__builtin_amdgcn_perm(q0[1], q0[0], SEL_LO),
                             __builtin_amdgcn_perm(q0[3], q0[2], SEL_LO),
                             __builtin_amdgcn_perm(q1[1], q1[0], SEL_LO),
                             __builtin_amdgcn_perm(q1[3], q1[2], SEL_LO));
        }
    }

    // ================= Phase B: 20 iterations, 1 barrier each, zero shuffles ==============
    int cur = 0;
    for (int t = 0; t < LL; ++t) {
        // B-frags: broadcast yx k-slices (every B column = yx -> every C column = w)
        bf16x8 bhi[3], blo[3];
        #pragma unroll
        for (int kt = 0; kt < 3; ++kt) {
            const unsigned* yp = &yxP[cur][kt * 32 + (lane >> 4) * 8];
            u32x4 q0 = *(const u32x4*)yp;
            u32x4 q1 = *(const u32x4*)(yp + 4);
            bhi[kt] = mk8(__builtin_amdgcn_perm(q0[1], q0[0], SEL_HI),
                          __builtin_amdgcn_perm(q0[3], q0[2], SEL_HI),
                          __builtin_amdgcn_perm(q1[1], q1[0], SEL_HI),
                          __builtin_amdgcn_perm(q1[3], q1[2], SEL_HI));
            blo[kt] = mk8(__builtin_amdgcn_perm(q0[1], q0[0], SEL_LO),
                          __builtin_amdgcn_perm(q0[3], q0[2], SEL_LO),
                          __builtin_amdgcn_perm(q1[1], q1[0], SEL_LO),
                          __builtin_amdgcn_perm(q1[3], q1[2], SEL_LO));
        }
        f32x4 a0 = {0.f,0.f,0.f,0.f}, a1 = {0.f,0.f,0.f,0.f}, a2 = {0.f,0.f,0.f,0.f};
        #pragma unroll
        for (int kt = 0; kt < 3; ++kt) {
            a0 = __builtin_amdgcn_mfma_f32_16x16x32_bf16(ahi[0][kt], bhi[kt], a0, 0, 0, 0);
            a0 = __builtin_amdgcn_mfma_f32_16x16x32_bf16(ahi[0][kt], blo[kt], a0, 0, 0, 0);
            a0 = __builtin_amdgcn_mfma_f32_16x16x32_bf16(alo[0][kt], bhi[kt], a0, 0, 0, 0);
            a1 = __builtin_amdgcn_mfma_f32_16x16x32_bf16(ahi[1][kt], bhi[kt], a1, 0, 0, 0);
            a1 = __builtin_amdgcn_mfma_f32_16x16x32_bf16(ahi[1][kt], blo[kt], a1, 0, 0, 0);
            a1 = __builtin_amdgcn_mfma_f32_16x16x32_bf16(alo[1][kt], bhi[kt], a1, 0, 0, 0);
            a2 = __builtin_amdgcn_mfma_f32_16x16x32_bf16(ahi[2][kt], bhi[kt], a2, 0, 0, 0);
            a2 = __builtin_amdgcn_mfma_f32_16x16x32_bf16(ahi[2][kt], blo[kt], a2, 0, 0, 0);
            a2 = __builtin_amdgcn_mfma_f32_16x16x32_bf16(alo[2][kt], bhi[kt], a2, 0, 0, 0);
        }
        // extract this lane's w (static register selects only)
        f32x4 am = (msel == 0) ? a0 : ((msel == 1) ? a1 : a2);
        float w  = (rsel == 0) ? am[0] : (rsel == 1) ? am[1] : (rsel == 2) ? am[2] : am[3];

        const float gs = pgs[t], es = pes[t], gm = pgm[t];
        if (act) {
            float xb  = fmaf(-2.0f * gs, w - hty, yx_own);
            float cen = 2.0f * fminf(fmaxf(rintf(xb * 0.5f), -1.0f), 1.0f);
            float z   = gm * (xb - cen);
            float e   = __expf(-z);
            float ply = fmaf(2.0f, __builtin_amdgcn_rcpf(1.0f + e), -1.0f);
            float yxn = fmaf(es, ply - x_c, ply);
            x_c    = ply;
            yx_own = yxn;
            yxP[cur ^ 1][row_g] = pack_hl(yxn);
        }
        cur ^= 1;
        __syncthreads();
    }

    // ---- epilogue: write x, accumulate loss ----
    float part = 0.f;
    if (act) {
        out[(size_t)b * NN + row_g] = x_c;
        float d = x_c - xt[(size_t)b * NN + row_g];
        part = d * d;
    }
    #pragma unroll
    for (int m = 1; m < 64; m <<= 1) part += __shfl_xor(part, m, 64);
    if (lane == 0) lsum[wid] = part;
    __syncthreads();
    if (tid == 0) atomicAdd(out + (size_t)NB * NN, lsum[0] + lsum[1]);
}

extern "C" void kernel_launch(void* const* d_in, const int* in_sizes, int n_in,
                              void* d_out, int out_size, void* d_ws, size_t ws_size,
                              hipStream_t stream) {
    const float* x_ini    = (const float*)d_in[0];
    const float* y        = (const float*)d_in[1];
    const float* H        = (const float*)d_in[2];
    const float* xt       = (const float*)d_in[3];
    const float* grad_ss  = (const float*)d_in[4];
    const float* extra_ss = (const float*)d_in[5];
    const float* gamma1   = (const float*)d_in[6];
    float* out = (float*)d_out;

    hipMemsetAsync(out + (size_t)NB * NN, 0, sizeof(float), stream);
    pg_kernel<<<NB, 128, 0, stream>>>(x_ini, y, H, xt, grad_ss, extra_ss, gamma1, out);
}

// Round 7
// 120.270 us; speedup vs baseline: 1.0654x; 1.0459x over previous
//
#include <hip/hip_runtime.h>

#define NB 4096
#define MM 128
#define NN 96
#define LL 20

typedef __attribute__((ext_vector_type(8))) short bf16x8;
typedef __attribute__((ext_vector_type(4))) float f32x4;
typedef __attribute__((ext_vector_type(4))) unsigned int u32x4;

// LDS union U (u32 words):
//  Phase A: Ht_p[112+ rows][67 u32] packed (hi|lo) bf16; row c = H column c
//           (row 96 = y, rows 97..111 garbage-read-only). [c][k] = H[kh*64+k][c].
//  Phase B: HTHP[96][100] packed u32, col 96 = HTy.
#define HTP_STRIDE  67
#define HTHP_STRIDE 100
#define U_WORDS     (NN * HTHP_STRIDE)   // 9600 u32 = 38.4KB (Ht_p: 112*67=7504 fits)

#define SEL_HI 0x07060302u
#define SEL_LO 0x05040100u

__device__ __forceinline__ unsigned bf16_rne(float f) {
    unsigned u = __float_as_uint(f);
    return (u + 0x7fffu + ((u >> 16) & 1u)) >> 16;
}
__device__ __forceinline__ unsigned pack_hl(float v) {
    unsigned hi = bf16_rne(v);
    unsigned lo = bf16_rne(v - __uint_as_float(hi << 16));
    return (hi << 16) | (lo & 0xffffu);
}
__device__ __forceinline__ bf16x8 mk8(unsigned a, unsigned b, unsigned c, unsigned d) {
    u32x4 t; t[0] = a; t[1] = b; t[2] = c; t[3] = d;
    return __builtin_bit_cast(bf16x8, t);
}
struct PairHL { bf16x8 hi, lo; };
__device__ __forceinline__ PairHL build_pair(const unsigned q[8]) {
    PairHL p;
    p.hi = mk8(__builtin_amdgcn_perm(q[1], q[0], SEL_HI), __builtin_amdgcn_perm(q[3], q[2], SEL_HI),
               __builtin_amdgcn_perm(q[5], q[4], SEL_HI), __builtin_amdgcn_perm(q[7], q[6], SEL_HI));
    p.lo = mk8(__builtin_amdgcn_perm(q[1], q[0], SEL_LO), __builtin_amdgcn_perm(q[3], q[2], SEL_LO),
               __builtin_amdgcn_perm(q[5], q[4], SEL_LO), __builtin_amdgcn_perm(q[7], q[6], SEL_LO));
    return p;
}

__global__ __launch_bounds__(256) __attribute__((amdgpu_waves_per_eu(4)))
void pg_kernel(const float* __restrict__ x_ini,
               const float* __restrict__ y,
               const float* __restrict__ H,
               const float* __restrict__ xt,
               const float* __restrict__ grad_ss,
               const float* __restrict__ extra_ss,
               const float* __restrict__ gamma1,
               float* __restrict__ out)
{
    __shared__ __align__(16) unsigned U[U_WORDS];
    __shared__ __align__(16) unsigned yxP[NN];
    __shared__ __align__(16) float wbuf[NN];
    __shared__ float pgs[LL], pes[LL], pgm[LL];
    __shared__ float lsum[4];

    const int b    = blockIdx.x;
    const int tid  = threadIdx.x;
    const int lane = tid & 63;
    const int wid  = tid >> 6;
    const int m15  = lane & 15;
    const int g4   = lane >> 4;      // k-group

    if (tid < LL) { pgs[tid] = grad_ss[tid]; pes[tid] = extra_ss[tid]; pgm[tid] = gamma1[tid]; }

    // ============ Phase A: HTH_ext = [H|y]^T [H|y], split-bf16 3-pass MFMA ============
    // wave owns J-tiles {wid, wid+4} (wid<3) or {wid} (wid==3); all 6 I-tiles.
    const int nJ = (wid == 3) ? 1 : 2;
    f32x4 acc[2][6];
    #pragma unroll
    for (int j = 0; j < 2; ++j)
        #pragma unroll
        for (int i = 0; i < 6; ++i)
            #pragma unroll
            for (int r = 0; r < 4; ++r) acc[j][i][r] = 0.f;

    const float* Hb = H + (size_t)b * (MM * NN);
    const int r16 = tid >> 2;    // 0..63: H row within half
    const int cg4 = tid & 3;     // col group: cols cg4*24 .. +23

    for (int kh = 0; kh < 2; ++kh) {
        if (kh) __syncthreads();   // previous half's frag reads complete
        // ---- stage: coalesced float4 row-chunk loads, packed transpose writes ----
        {
            const float* src = Hb + (size_t)(kh * 64 + r16) * NN + cg4 * 24;
            float4 vv[6];
            #pragma unroll
            for (int i = 0; i < 6; ++i) vv[i] = *(const float4*)(src + 4 * i);
            #pragma unroll
            for (int i = 0; i < 6; ++i) {
                const int c = cg4 * 24 + 4 * i;
                U[(c + 0) * HTP_STRIDE + r16] = pack_hl(vv[i].x);
                U[(c + 1) * HTP_STRIDE + r16] = pack_hl(vv[i].y);
                U[(c + 2) * HTP_STRIDE + r16] = pack_hl(vv[i].z);
                U[(c + 3) * HTP_STRIDE + r16] = pack_hl(vv[i].w);
            }
            if (tid < 64)
                U[96 * HTP_STRIDE + tid] = pack_hl(y[(size_t)b * MM + kh * 64 + tid]);
        }
        __syncthreads();

        // ---- MFMA over this half's k (2 steps of K=32) ----
        #pragma unroll
        for (int kk = 0; kk < 2; ++kk) {
            const int kbase = kk * 32 + g4 * 8;
            PairHL B[2];
            #pragma unroll
            for (int j = 0; j < 2; ++j) {
                if (j < nJ) {
                    const int J = wid + 4 * j;
                    unsigned q[8];
                    const unsigned* p = &U[(J * 16 + m15) * HTP_STRIDE + kbase];
                    #pragma unroll
                    for (int u = 0; u < 8; ++u) q[u] = p[u];
                    B[j] = build_pair(q);
                }
            }
            #pragma unroll
            for (int I = 0; I < 6; ++I) {
                unsigned q[8];
                const unsigned* p = &U[(I * 16 + m15) * HTP_STRIDE + kbase];
                #pragma unroll
                for (int u = 0; u < 8; ++u) q[u] = p[u];
                PairHL A = build_pair(q);
                #pragma unroll
                for (int j = 0; j < 2; ++j) {
                    if (j < nJ) {
                        acc[j][I] = __builtin_amdgcn_mfma_f32_16x16x32_bf16(A.hi, B[j].hi, acc[j][I], 0, 0, 0);
                        acc[j][I] = __builtin_amdgcn_mfma_f32_16x16x32_bf16(A.hi, B[j].lo, acc[j][I], 0, 0, 0);
                        acc[j][I] = __builtin_amdgcn_mfma_f32_16x16x32_bf16(A.lo, B[j].hi, acc[j][I], 0, 0, 0);
                    }
                }
            }
        }
    }
    __syncthreads();   // all frag reads done -> overwrite U with HTHP

    // ---- C-write: [m89-verified] col = J*16 + m15, row = I*16 + g4*4 + r ----
    #pragma unroll
    for (int j = 0; j < 2; ++j) {
        if (j < nJ) {
            const int col = (wid + 4 * j) * 16 + m15;
            if (col <= 96) {
                #pragma unroll
                for (int I = 0; I < 6; ++I) {
                    const int rowb = I * 16 + g4 * 4;
                    #pragma unroll
                    for (int r = 0; r < 4; ++r)
                        U[(rowb + r) * HTHP_STRIDE + col] = pack_hl(acc[j][I][r]);
                }
            }
        }
    }
    __syncthreads();   // HTHP visible

    // ============ Phase B setup ============
    float yx_own = 0.f, x_c = 0.f, hty = 0.f;
    if (tid < NN) {
        yx_own = x_ini[(size_t)b * NN + tid];
        x_c    = yx_own;
        yxP[tid] = pack_hl(yx_own);
        unsigned p = U[tid * HTHP_STRIDE + 96];
        hty = __uint_as_float(p & 0xffff0000u) + __uint_as_float(p << 16);
    }
    // persistent A-frags: wave owns I-tiles {wid, wid+4} (wid<2) else {wid}
    const int nI = (wid < 2) ? 2 : 1;
    bf16x8 ahi[2][3], alo[2][3];
    #pragma unroll
    for (int t2 = 0; t2 < 2; ++t2) {
        if (t2 < nI) {
            const int I = wid + 4 * t2;
            #pragma unroll
            for (int kk = 0; kk < 3; ++kk) {
                unsigned q[8];
                const unsigned* p = &U[(I * 16 + m15) * HTHP_STRIDE + kk * 32 + g4 * 8];
                #pragma unroll
                for (int u = 0; u < 8; ++u) q[u] = p[u];
                PairHL A = build_pair(q);
                ahi[t2][kk] = A.hi;
                alo[t2][kk] = A.lo;
            }
        }
    }
    __syncthreads();   // yxP[0] published

    // ============ Phase B: 20 iterations ============
    for (int t = 0; t < LL; ++t) {
        // broadcast B-frags from yxP (same addr within k-group -> conflict-free)
        bf16x8 bhi[3], blo[3];
        #pragma unroll
        for (int kk = 0; kk < 3; ++kk) {
            unsigned q[8];
            const unsigned* p = &yxP[kk * 32 + g4 * 8];
            #pragma unroll
            for (int u = 0; u < 8; ++u) q[u] = p[u];
            PairHL Bp = build_pair(q);
            bhi[kk] = Bp.hi; blo[kk] = Bp.lo;
        }
        f32x4 a0 = {0.f,0.f,0.f,0.f}, a1 = {0.f,0.f,0.f,0.f};
        #pragma unroll
        for (int kk = 0; kk < 3; ++kk) {
            a0 = __builtin_amdgcn_mfma_f32_16x16x32_bf16(ahi[0][kk], bhi[kk], a0, 0, 0, 0);
            a0 = __builtin_amdgcn_mfma_f32_16x16x32_bf16(ahi[0][kk], blo[kk], a0, 0, 0, 0);
            a0 = __builtin_amdgcn_mfma_f32_16x16x32_bf16(alo[0][kk], bhi[kk], a0, 0, 0, 0);
            if (1 < nI) {
                a1 = __builtin_amdgcn_mfma_f32_16x16x32_bf16(ahi[1][kk], bhi[kk], a1, 0, 0, 0);
                a1 = __builtin_amdgcn_mfma_f32_16x16x32_bf16(ahi[1][kk], blo[kk], a1, 0, 0, 0);
                a1 = __builtin_amdgcn_mfma_f32_16x16x32_bf16(alo[1][kk], bhi[kk], a1, 0, 0, 0);
            }
        }
        // lane m15==0 publishes w for its 4 rows per tile (acc[r] = w[I*16+g4*4+r])
        if (m15 == 0) {
            const int rb0 = wid * 16 + g4 * 4;
            wbuf[rb0 + 0] = a0[0]; wbuf[rb0 + 1] = a0[1];
            wbuf[rb0 + 2] = a0[2]; wbuf[rb0 + 3] = a0[3];
            if (1 < nI) {
                const int rb1 = (wid + 4) * 16 + g4 * 4;
                wbuf[rb1 + 0] = a1[0]; wbuf[rb1 + 1] = a1[1];
                wbuf[rb1 + 2] = a1[2]; wbuf[rb1 + 3] = a1[3];
            }
        }
        __syncthreads();   // B1: wbuf visible

        if (tid < NN) {
            float w = wbuf[tid];
            const float gs = pgs[t], es = pes[t], gm = pgm[t];
            float xb  = fmaf(-2.0f * gs, w - hty, yx_own);
            float cen = 2.0f * fminf(fmaxf(rintf(xb * 0.5f), -1.0f), 1.0f);
            float z   = gm * (xb - cen);
            float e   = __expf(-z);
            float ply = fmaf(2.0f, __builtin_amdgcn_rcpf(1.0f + e), -1.0f);
            float yxn = fmaf(es, ply - x_c, ply);
            x_c    = ply;
            yx_own = yxn;
            yxP[tid] = pack_hl(yxn);
        }
        __syncthreads();   // B2: yxP published
    }

    // ============ epilogue ============
    float part = 0.f;
    if (tid < NN) {
        out[(size_t)b * NN + tid] = x_c;
        float d = x_c - xt[(size_t)b * NN + tid];
        part = d * d;
    }
    #pragma unroll
    for (int m = 1; m < 64; m <<= 1) part += __shfl_xor(part, m, 64);
    if (lane == 0) lsum[wid] = part;
    __syncthreads();
    if (tid == 0) atomicAdd(out + (size_t)NB * NN, (lsum[0] + lsum[1]) + (lsum[2] + lsum[3]));
}

extern "C" void kernel_launch(void* const* d_in, const int* in_sizes, int n_in,
                              void* d_out, int out_size, void* d_ws, size_t ws_size,
                              hipStream_t stream) {
    const float* x_ini    = (const float*)d_in[0];
    const float* y        = (const float*)d_in[1];
    const float* H        = (const float*)d_in[2];
    const float* xt       = (const float*)d_in[3];
    const float* grad_ss  = (const float*)d_in[4];
    const float* extra_ss = (const float*)d_in[5];
    const float* gamma1   = (const float*)d_in[6];
    float* out = (float*)d_out;

    hipMemsetAsync(out + (size_t)NB * NN, 0, sizeof(float), stream);
    pg_kernel<<<NB, 256, 0, stream>>>(x_ini, y, H, xt, grad_ss, extra_ss, gamma1, out);
}